// Round 4
// baseline (138.616 us; speedup 1.0000x reference)
//
#include <hip/hip_runtime.h>

#define QDIM 192
#define KDIM 64
#define CDIM 256
#define DOUT 128
#define CAPS 64     // adjacency slots per sub-bucket; per-sub deg ~ Poisson(8), P(>=64) ~ 1e-38
#define NVCOL 640   // virtual col space: [q 0:256 | k 256:512 | v 512:576 | s 576:640]
#define NEG_INF __int_as_float(0xFF800000)

typedef _Float16 hf2 __attribute__((ext_vector_type(2)));
typedef _Float16 half4 __attribute__((ext_vector_type(4)));
typedef _Float16 half8 __attribute__((ext_vector_type(8)));
typedef float floatx4 __attribute__((ext_vector_type(4)));

#if defined(__has_builtin)
#if __has_builtin(__builtin_amdgcn_fdot2)
#define HAVE_FDOT2 1
#endif
#endif

__device__ __forceinline__ hf2 bc_h2(unsigned u) { return __builtin_bit_cast(hf2, u); }

__device__ __forceinline__ float dot2acc(hf2 a, hf2 b, float c) {
#ifdef HAVE_FDOT2
    return __builtin_amdgcn_fdot2(a, b, c, false);
#else
    return c + (float)a[0] * (float)b[0] + (float)a[1] * (float)b[1];
#endif
}

// prep: 1) query fp32->fp16  2) WhT[640][192] fp16 pre-transposed W
//       3) OB[640][64] fused one-hot+bias  4) deg4 init (4 sub-counters/node):
//          0 for masked nodes (binary search over sorted mask), INT_MIN otherwise.
//          Unmasked counters are NEVER atomically touched (scatter mask-skips),
//          so a plain sign-test in gemm is race-free.
__global__ __launch_bounds__(256) void prep_kernel(
        const float* __restrict__ query, _Float16* __restrict__ Qh,
        const float* __restrict__ Wq, const float* __restrict__ bq,
        const float* __restrict__ Wk, const float* __restrict__ bk,
        const float* __restrict__ Wv, const float* __restrict__ bv,
        const float* __restrict__ Ws, const float* __restrict__ bs,
        const int* __restrict__ mask, int M,
        _Float16* __restrict__ WhT, float* __restrict__ OB,
        int* __restrict__ deg4, int qchunks, int N) {
    int t = blockIdx.x * blockDim.x + threadIdx.x;
    if (t < qchunks) {
        float4 v = ((const float4*)query)[t];
        half4 h = { (_Float16)v.x, (_Float16)v.y, (_Float16)v.z, (_Float16)v.w };
        ((half4*)Qh)[t] = h;
        return;
    }
    t -= qchunks;
    if (t < NVCOL * QDIM) {
        int v = t / QDIM, r = t - v * QDIM;
        const float* Wseg; int col;
        if (v < 256)      { Wseg = Wq; col = v; }
        else if (v < 512) { Wseg = Wk; col = v - 256; }
        else if (v < 576) { Wseg = Wv; col = QDIM + (v - 512); }
        else              { Wseg = Ws; col = QDIM + (v - 576); }
        WhT[t] = (_Float16)Wseg[(size_t)r * CDIM + col];
        return;
    }
    t -= NVCOL * QDIM;
    if (t < NVCOL * KDIM) {
        int v = t >> 6, kidx = t & 63;
        const float* Wseg; const float* bseg; int col;
        if (v < 256)      { Wseg = Wq; bseg = bq; col = v; }
        else if (v < 512) { Wseg = Wk; bseg = bk; col = v - 256; }
        else if (v < 576) { Wseg = Wv; bseg = bv; col = QDIM + (v - 512); }
        else              { Wseg = Ws; bseg = bs; col = QDIM + (v - 576); }
        OB[t] = Wseg[(size_t)(QDIM + kidx) * CDIM + col] + bseg[col];
        return;
    }
    t -= NVCOL * KDIM;
    if (t < 4 * N) {
        int node = t >> 2;
        int lo = 0, hi = M;
        while (lo < hi) { int mid = (lo + hi) >> 1; if (mask[mid] < node) lo = mid + 1; else hi = mid; }
        bool found = (lo < M) && (mask[lo] == node);
        deg4[t] = found ? 0 : (int)0x80000000;
    }
}

// MFMA node GEMM, barrier-free & LDS-free:
//  - fragments loaded straight from global (Qh is L2-resident; the 24.6 KB WhT
//    col-tile is L1-resident) in the exact 16B-per-lane MFMA layout
//  - no __syncthreads -> no vmcnt(0) drain points; occupancy no longer LDS-capped
//  - duplicate/clamped rows produce identical values -> redundant racing writes
//    are benign; all dedup guards and the rowmap are gone
//  - z=0: K+V tiles (cols 256..575) for all rows + edge-scatter duty
//    (cheap gated loads issued first, contended atomic issued LAST so only the
//    wave's own exit waits on it); z=1: Q+S tiles for masked rows
__global__ __launch_bounds__(256) void gemm_nodes(
        const _Float16* __restrict__ Qh, const int* __restrict__ key_idx,
        const _Float16* __restrict__ WhT, const float* __restrict__ OB,
        const int* __restrict__ esrc, const int* __restrict__ edst,
        const int* __restrict__ mask, int M,
        int* deg4, int* __restrict__ adj, int E,
        _Float16* __restrict__ Qbuf, _Float16* __restrict__ Kbuf,
        _Float16* __restrict__ Vbuf, float* __restrict__ Sbuf, int N) {
    int tid = threadIdx.x;
    int z = blockIdx.z;
    int bm = blockIdx.x * 64;

    // edge duty (z=0): gated loads now, heavy atomic at the very end
    bool doe[2] = {false, false};
    int srcv[2]; size_t ci[2] = {0, 0};
    if (z == 0) {
        int stride = gridDim.x * gridDim.y * 256;
        int base = (blockIdx.y * gridDim.x + blockIdx.x) * 256 + tid;
        #pragma unroll
        for (int q = 0; q < 2; q++) {
            int e = base + q * stride;
            if (e < E) {
                int d = edst[e];
                size_t c = (size_t)d * 4 + (e & 3);
                if (deg4[c] >= 0) {            // masked dst only
                    doe[q] = true; srcv[q] = esrc[e]; ci[q] = c;
                }
            }
        }
        if (bm >= N) {   // degenerate guard: still honor scatter duty
            #pragma unroll
            for (int q = 0; q < 2; q++)
                if (doe[q]) { int s = atomicAdd(&deg4[ci[q]], 1); if ((unsigned)s < CAPS) adj[ci[q] * CAPS + s] = srcv[q]; }
            return;
        }
    } else {
        if (bm >= M) return;
    }

    // bn: virtual col base for this class
    int bn = (z == 0) ? 256 + blockIdx.y * 64
                      : (blockIdx.y < 4 ? blockIdx.y * 64 : 576);

    int w = tid >> 6, l = tid & 63;
    int lrow = l & 15, quad = l >> 4;

    // A fragments: row (w*16+lrow), k-chunks quad*8 + ks*32 -- 6 x 16B loads
    int ra = w * 16 + lrow;
    int gra = (z == 0) ? min(bm + ra, N - 1) : mask[min(bm + ra, M - 1)];
    const _Float16* abase = Qh + (size_t)gra * QDIM + quad * 8;
    half8 af[6];
    #pragma unroll
    for (int ks = 0; ks < 6; ks++) af[ks] = *(const half8*)(abase + ks * 32);

    floatx4 acc[4] = {{0.f,0.f,0.f,0.f},{0.f,0.f,0.f,0.f},{0.f,0.f,0.f,0.f},{0.f,0.f,0.f,0.f}};
    #pragma unroll
    for (int nt = 0; nt < 4; nt++) {
        const _Float16* bbase = WhT + (size_t)(bn + nt * 16 + lrow) * QDIM + quad * 8;
        #pragma unroll
        for (int ks = 0; ks < 6; ks++) {
            half8 bf = *(const half8*)(bbase + ks * 32);
            acc[nt] = __builtin_amdgcn_mfma_f32_16x16x32_f16(af[ks], bf, acc[nt], 0, 0, 0);
        }
    }

    // epilogue: D(row = gr(w*16+quad*4+reg), col = bn + nt*16 + lrow)
    // clamped/duplicate rows write identical values -> benign redundancy
    int ki[4], grs[4];
    #pragma unroll
    for (int reg = 0; reg < 4; reg++) {
        int re = w * 16 + quad * 4 + reg;
        grs[reg] = (z == 0) ? min(bm + re, N - 1) : mask[min(bm + re, M - 1)];
        ki[reg] = key_idx[grs[reg]];
    }
    #pragma unroll
    for (int nt = 0; nt < 4; nt++) {
        int gc = bn + nt * 16 + lrow;
        const float* obc = OB + (size_t)gc * KDIM;
        #pragma unroll
        for (int reg = 0; reg < 4; reg++) {
            int gr = grs[reg];
            float v = acc[nt][reg] + obc[ki[reg]];
            if (gc < 256)      Qbuf[(size_t)gr * 256 + gc] = (_Float16)v;
            else if (gc < 512) Kbuf[(size_t)gr * 256 + (gc - 256)] = (_Float16)v;
            else if (gc < 576) Vbuf[(size_t)gr * KDIM + (gc - 512)] = (_Float16)v;
            else               Sbuf[(size_t)gr * KDIM + (gc - 576)] = v;
        }
    }

    // contended atomic last: only this wave's exit waits on it; other resident
    // waves (no barriers, ~2x occupancy) keep the CU busy
    #pragma unroll
    for (int q = 0; q < 2; q++)
        if (doe[q]) { int s = atomicAdd(&deg4[ci[q]], 1); if ((unsigned)s < CAPS) adj[ci[q] * CAPS + s] = srcv[q]; }
}

// 1 wave per output-run (masked node): the 4 sub-buckets are walked as one
// concatenated list, round-robin across the 4 groups (prefix-offset mapping,
// trip counts differ by <=1 -> balanced). Software-pipelined gather,
// private online-softmax per group, single end-merge,
// fused relu + 64x128 GEMV into d_out. 4 rows/block.
__global__ __launch_bounds__(256) void attend_out(
        const _Float16* __restrict__ Qbuf, const _Float16* __restrict__ Kbuf,
        const _Float16* __restrict__ Vbuf, const float* __restrict__ Sbuf,
        const int* __restrict__ deg4, const int* __restrict__ adj,
        const int* __restrict__ mask, const float* __restrict__ Wo,
        const float* __restrict__ bo, float* __restrict__ out, int M) {
    int w = threadIdx.x >> 6, lane = threadIdx.x & 63;
    int r = blockIdx.x * 4 + w;
    if (r >= M) return;
    int node = mask[r];
    if (r > 0 && mask[r - 1] == node) return;   // duplicate run: start-wave writes it
    int l = lane & 15, g = lane >> 4;

    const uint4* qp = (const uint4*)(Qbuf + (size_t)node * 256 + l * 16);
    uint4 qa = qp[0], qb = qp[1];
    hf2 qh[8] = { bc_h2(qa.x), bc_h2(qa.y), bc_h2(qa.z), bc_h2(qa.w),
                  bc_h2(qb.x), bc_h2(qb.y), bc_h2(qb.z), bc_h2(qb.w) };

    // concatenated-list geometry
    int dn_g = min(deg4[(size_t)node * 4 + g], CAPS);
    int d0 = __shfl(dn_g, 0, 64), d1 = __shfl(dn_g, 16, 64);
    int d2 = __shfl(dn_g, 32, 64), d3 = __shfl(dn_g, 48, 64);
    int O1 = d0, O2 = d0 + d1, O3 = d0 + d1 + d2, T = O3 + d3;
    const size_t base4 = (size_t)node * 4 * CAPS;
    auto fs = [&](int j) -> int {
        int b = (j >= O1) + (j >= O2) + (j >= O3);
        int off = j - (b == 0 ? 0 : b == 1 ? O1 : b == 2 ? O2 : O3);
        return adj[base4 + (size_t)b * CAPS + off];
    };

    // private per-group state: m, dsum uniform in group; acc = 4 V-cols per lane
    float m = NEG_INF, dsum = 0.f;
    float a0 = 0.f, a1 = 0.f, a2 = 0.f, a3 = 0.f;

    uint4 ka, kb; uint2 vv; int s_nxt = 0;
    if (g < T) {
        int s0 = fs(g);
        const uint4* kp = (const uint4*)(Kbuf + (size_t)s0 * 256 + l * 16);
        ka = kp[0]; kb = kp[1];
        vv = *(const uint2*)(Vbuf + (size_t)s0 * KDIM + l * 4);
        s_nxt = (g + 4 < T) ? fs(g + 4) : s0;
    }
    for (int j = g; j < T; j += 4) {
        // prefetch next position's K/V (index already resident from last iter)
        const uint4* kp2 = (const uint4*)(Kbuf + (size_t)s_nxt * 256 + l * 16);
        uint4 ka2 = kp2[0], kb2 = kp2[1];
        uint2 vv2 = *(const uint2*)(Vbuf + (size_t)s_nxt * KDIM + l * 4);
        int s_aft = (j + 8 < T) ? fs(j + 8) : s_nxt;

        float d = 0.f;
        d = dot2acc(bc_h2(ka.x), qh[0], d);
        d = dot2acc(bc_h2(ka.y), qh[1], d);
        d = dot2acc(bc_h2(ka.z), qh[2], d);
        d = dot2acc(bc_h2(ka.w), qh[3], d);
        d = dot2acc(bc_h2(kb.x), qh[4], d);
        d = dot2acc(bc_h2(kb.y), qh[5], d);
        d = dot2acc(bc_h2(kb.z), qh[6], d);
        d = dot2acc(bc_h2(kb.w), qh[7], d);
        d += __shfl_xor(d, 1, 64);
        d += __shfl_xor(d, 2, 64);
        d += __shfl_xor(d, 4, 64);
        d += __shfl_xor(d, 8, 64);
        float sc = d * 0.0625f;              // 1/sqrt(256)
        float m_new = fmaxf(m, sc);
        float scale = __expf(m - m_new);     // first edge: exp(-inf)=0
        float p = __expf(sc - m_new);
        dsum = dsum * scale + p;
        hf2 v01 = bc_h2(vv.x), v23 = bc_h2(vv.y);
        a0 = a0 * scale + p * (float)v01[0];
        a1 = a1 * scale + p * (float)v01[1];
        a2 = a2 * scale + p * (float)v23[0];
        a3 = a3 * scale + p * (float)v23[1];
        m = m_new;
        ka = ka2; kb = kb2; vv = vv2; s_nxt = s_aft;
    }

    // merge the 4 groups (m, dsum group-uniform)
    float Mx = fmaxf(m, __shfl_xor(m, 16, 64));
    Mx = fmaxf(Mx, __shfl_xor(Mx, 32, 64));
    float wgt = (m == NEG_INF) ? 0.f : __expf(m - Mx);   // empty group / T==0
    float ds = dsum * wgt;
    ds += __shfl_xor(ds, 16, 64);
    ds += __shfl_xor(ds, 32, 64);
    a0 *= wgt; a1 *= wgt; a2 *= wgt; a3 *= wgt;
    a0 += __shfl_xor(a0, 16, 64); a0 += __shfl_xor(a0, 32, 64);
    a1 += __shfl_xor(a1, 16, 64); a1 += __shfl_xor(a1, 32, 64);
    a2 += __shfl_xor(a2, 16, 64); a2 += __shfl_xor(a2, 32, 64);
    a3 += __shfl_xor(a3, 16, 64); a3 += __shfl_xor(a3, 32, 64);
    float inv = 1.f / (ds + 1e-16f);

    // h cols l*4..l*4+3 (identical across groups)
    float4 s4 = *((const float4*)(Sbuf + (size_t)node * KDIM + l * 4));
    float h0 = fmaxf(a0 * inv + s4.x, 0.f);
    float h1 = fmaxf(a1 * inv + s4.y, 0.f);
    float h2 = fmaxf(a2 * inv + s4.z, 0.f);
    float h3 = fmaxf(a3 * inv + s4.w, 0.f);

    // GEMV: out(row) = h @ Wo + bo
    float o0 = bo[lane], o1 = bo[lane + 64];
    #pragma unroll
    for (int c = 0; c < KDIM; c++) {
        float hc = (c & 3) == 0 ? h0 : (c & 3) == 1 ? h1 : (c & 3) == 2 ? h2 : h3;
        float hv = __shfl(hc, c >> 2, 64);
        o0 += hv * Wo[c * DOUT + lane];
        o1 += hv * Wo[c * DOUT + 64 + lane];
    }
    int rr = r;
    do {
        out[(size_t)rr * DOUT + lane] = o0;
        out[(size_t)rr * DOUT + 64 + lane] = o1;
        rr++;
    } while (rr < M && mask[rr] == node);
}

extern "C" void kernel_launch(void* const* d_in, const int* in_sizes, int n_in,
                              void* d_out, int out_size, void* d_ws, size_t ws_size,
                              hipStream_t stream) {
    const float* query    = (const float*)d_in[0];
    const int* key_idx    = (const int*)d_in[1];
    const int* edge_index = (const int*)d_in[2];
    const int* mask_idx   = (const int*)d_in[3];
    const float* Wq = (const float*)d_in[4];
    const float* bq = (const float*)d_in[5];
    const float* Wk = (const float*)d_in[6];
    const float* bk = (const float*)d_in[7];
    const float* Wv = (const float*)d_in[8];
    const float* bv = (const float*)d_in[9];
    const float* Ws = (const float*)d_in[10];
    const float* bs = (const float*)d_in[11];
    const float* Wo = (const float*)d_in[12];
    const float* bo = (const float*)d_in[13];

    int N = in_sizes[0] / QDIM;
    int E = in_sizes[2] / 2;
    int M = in_sizes[3];
    const int* esrc = edge_index;
    const int* edst = edge_index + E;

    char* wsb = (char*)d_ws;
    size_t off = 0;
    auto alloc = [&](size_t nbytes) { char* p = wsb + off; off += (nbytes + 15) & ~15ull; return p; };
    _Float16* Qh   = (_Float16*)alloc((size_t)N * QDIM * 2);
    _Float16* WhT  = (_Float16*)alloc((size_t)NVCOL * QDIM * 2);
    float* OB      = (float*)alloc((size_t)NVCOL * KDIM * 4);
    _Float16* Qbuf = (_Float16*)alloc((size_t)N * 256 * 2);
    _Float16* Kbuf = (_Float16*)alloc((size_t)N * 256 * 2);
    _Float16* Vbuf = (_Float16*)alloc((size_t)N * KDIM * 2);
    float* Sbuf    = (float*)alloc((size_t)N * KDIM * 4);
    int*   deg4    = (int*)alloc((size_t)N * 4 * 4);
    int*   adj     = (int*)alloc((size_t)N * 4 * CAPS * 4);

    int qchunks = N * QDIM / 4;   // float4 chunks of query
    int total1 = qchunks + NVCOL * QDIM + NVCOL * KDIM + 4 * N;
    prep_kernel<<<(total1 + 255) / 256, 256, 0, stream>>>(
        query, Qh, Wq, bq, Wk, bk, Wv, bv, Ws, bs, mask_idx, M, WhT, OB, deg4, qchunks, N);

    int xa = (N + 63) / 64, xm = (M + 63) / 64;
    dim3 ggrid((unsigned)max(xa, xm), 5, 2);   // z=0: K/V all rows; z=1: Q/S masked rows
    gemm_nodes<<<ggrid, 256, 0, stream>>>(Qh, key_idx, WhT, OB, esrc, edst,
                                          mask_idx, M, deg4, adj, E,
                                          Qbuf, Kbuf, Vbuf, Sbuf, N);

    attend_out<<<(M + 3) / 4, 256, 0, stream>>>(Qbuf, Kbuf, Vbuf, Sbuf, deg4, adj,
                                                mask_idx, Wo, bo, (float*)d_out, M);
}

// Round 5
// 131.892 us; speedup vs baseline: 1.0510x; 1.0510x over previous
//
#include <hip/hip_runtime.h>

#define QDIM 192
#define KDIM 64
#define CDIM 256
#define DOUT 128
#define CAPS 64     // adjacency slots per sub-bucket; per-sub deg ~ Poisson(8), P(>=64) ~ 1e-38
#define NVCOL 640   // virtual col space: [q 0:256 | k 256:512 | v 512:576 | s 576:640]
#define NEG_INF __int_as_float(0xFF800000)
#define LDP 200     // LDS row pitch in halves (192 + 8 pad)

typedef _Float16 hf2 __attribute__((ext_vector_type(2)));
typedef _Float16 half4 __attribute__((ext_vector_type(4)));
typedef _Float16 half8 __attribute__((ext_vector_type(8)));
typedef float floatx4 __attribute__((ext_vector_type(4)));

#if defined(__has_builtin)
#if __has_builtin(__builtin_amdgcn_fdot2)
#define HAVE_FDOT2 1
#endif
#endif

__device__ __forceinline__ hf2 bc_h2(unsigned u) { return __builtin_bit_cast(hf2, u); }

__device__ __forceinline__ float dot2acc(hf2 a, hf2 b, float c) {
#ifdef HAVE_FDOT2
    return __builtin_amdgcn_fdot2(a, b, c, false);
#else
    return c + (float)a[0] * (float)b[0] + (float)a[1] * (float)b[1];
#endif
}

// prep: 1) query fp32->fp16  2) WhT[640][192] fp16 pre-transposed W
//       3) OB[640][64] fused one-hot+bias  4) deg4 init (4 sub-counters/node):
//          0 for masked nodes (binary search over sorted mask), INT_MIN otherwise.
__global__ __launch_bounds__(256) void prep_kernel(
        const float* __restrict__ query, _Float16* __restrict__ Qh,
        const float* __restrict__ Wq, const float* __restrict__ bq,
        const float* __restrict__ Wk, const float* __restrict__ bk,
        const float* __restrict__ Wv, const float* __restrict__ bv,
        const float* __restrict__ Ws, const float* __restrict__ bs,
        const int* __restrict__ mask, int M,
        _Float16* __restrict__ WhT, float* __restrict__ OB,
        int* __restrict__ deg4, int qchunks, int N) {
    int t = blockIdx.x * blockDim.x + threadIdx.x;
    if (t < qchunks) {
        float4 v = ((const float4*)query)[t];
        half4 h = { (_Float16)v.x, (_Float16)v.y, (_Float16)v.z, (_Float16)v.w };
        ((half4*)Qh)[t] = h;
        return;
    }
    t -= qchunks;
    if (t < NVCOL * QDIM) {
        int v = t / QDIM, r = t - v * QDIM;
        const float* Wseg; int col;
        if (v < 256)      { Wseg = Wq; col = v; }
        else if (v < 512) { Wseg = Wk; col = v - 256; }
        else if (v < 576) { Wseg = Wv; col = QDIM + (v - 512); }
        else              { Wseg = Ws; col = QDIM + (v - 576); }
        WhT[t] = (_Float16)Wseg[(size_t)r * CDIM + col];
        return;
    }
    t -= NVCOL * QDIM;
    if (t < NVCOL * KDIM) {
        int v = t >> 6, kidx = t & 63;
        const float* Wseg; const float* bseg; int col;
        if (v < 256)      { Wseg = Wq; bseg = bq; col = v; }
        else if (v < 512) { Wseg = Wk; bseg = bk; col = v - 256; }
        else if (v < 576) { Wseg = Wv; bseg = bv; col = QDIM + (v - 512); }
        else              { Wseg = Ws; bseg = bs; col = QDIM + (v - 576); }
        OB[t] = Wseg[(size_t)(QDIM + kidx) * CDIM + col] + bseg[col];
        return;
    }
    t -= NVCOL * KDIM;
    if (t < 4 * N) {
        int node = t >> 2;
        int lo = 0, hi = M;
        while (lo < hi) { int mid = (lo + hi) >> 1; if (mask[mid] < node) lo = mid + 1; else hi = mid; }
        bool found = (lo < M) && (mask[lo] == node);
        deg4[t] = found ? 0 : (int)0x80000000;
    }
}

// MFMA node GEMM, hybrid staging + fused de-contended scatter:
//  - A fragments DIRECT from global (read exactly once per block; issued
//    pre-barrier so they drain for free during Bs staging)
//  - B tile in LDS (16x reuse; L1 would thrash across co-resident blocks)
//  - LDS 25.6 KB -> 6 blocks/CU; single barrier
//  - clamped per-lane row indices (duplicate writes benign; no rowmap)
//  - z=0: K+V cols 256..575, all rows + edge-scatter duty (atomic post-barrier,
//    consumed post-MFMA); z=1: Q+S cols for masked rows
__global__ __launch_bounds__(256) void gemm_nodes(
        const _Float16* __restrict__ Qh, const int* __restrict__ key_idx,
        const _Float16* __restrict__ WhT, const float* __restrict__ OB,
        const int* __restrict__ esrc, const int* __restrict__ edst,
        const int* __restrict__ mask, int M,
        int* deg4, int* __restrict__ adj, int E,
        _Float16* __restrict__ Qbuf, _Float16* __restrict__ Kbuf,
        _Float16* __restrict__ Vbuf, float* __restrict__ Sbuf, int N) {
    __shared__ __align__(16) _Float16 Bs[64 * LDP];
    int tid = threadIdx.x;
    int z = blockIdx.z;
    int bm = blockIdx.x * 64;

    // edge duty (z=0): gated loads now, contended atomic after the barrier
    bool doe[2] = {false, false};
    int srcv[2]; size_t ci[2] = {0, 0};
    if (z == 0) {
        int stride = gridDim.x * gridDim.y * 256;
        int base = (blockIdx.y * gridDim.x + blockIdx.x) * 256 + tid;
        #pragma unroll
        for (int q = 0; q < 2; q++) {
            int e = base + q * stride;
            if (e < E) {
                int d = edst[e];
                size_t c = (size_t)d * 4 + (e & 3);
                if (deg4[c] >= 0) {            // masked dst only
                    doe[q] = true; srcv[q] = esrc[e]; ci[q] = c;
                }
            }
        }
    } else {
        if (bm >= M) return;
    }

    // bn: virtual col base for this class
    int bn = (z == 0) ? 256 + blockIdx.y * 64
                      : (blockIdx.y < 4 ? blockIdx.y * 64 : 576);

    int w = tid >> 6, l = tid & 63;
    int lrow = l & 15, quad = l >> 4;

    // A fragments: row (w*16+lrow), 16B chunks at quad*16 + ks*64 bytes.
    // Per ks, a wave covers one contiguous 64B run per row -> coalesced.
    int ra = w * 16 + lrow;
    int gra = (z == 0) ? min(bm + ra, N - 1) : mask[min(bm + ra, M - 1)];
    const _Float16* abase = Qh + (size_t)gra * QDIM + quad * 8;
    half8 af[6];
    #pragma unroll
    for (int ks = 0; ks < 6; ks++) af[ks] = *(const half8*)(abase + ks * 32);

    // B tile: 64 virtual cols x 192 halves = 1536 uint4; 6 per thread
    #pragma unroll
    for (int it = 0; it < 6; it++) {
        int idx = tid + it * 256;            // 0..1535
        int cc = idx / 24, q4 = idx % 24;
        uint4 vb = ((const uint4*)(WhT + (size_t)(bn + cc) * QDIM))[q4];
        *((uint4*)&Bs[cc * LDP + q4 * 8]) = vb;
    }
    __syncthreads();

    // issue contended atomics now; latency hides under ds_read+MFMA below
    int slot[2] = {-1, -1};
    #pragma unroll
    for (int q = 0; q < 2; q++) if (doe[q]) slot[q] = atomicAdd(&deg4[ci[q]], 1);

    floatx4 acc[4] = {{0.f,0.f,0.f,0.f},{0.f,0.f,0.f,0.f},{0.f,0.f,0.f,0.f},{0.f,0.f,0.f,0.f}};
    #pragma unroll
    for (int ks = 0; ks < 6; ks++) {
        #pragma unroll
        for (int nt = 0; nt < 4; nt++) {
            half8 bf = *(const half8*)(&Bs[(nt * 16 + lrow) * LDP + quad * 8 + ks * 32]);
            acc[nt] = __builtin_amdgcn_mfma_f32_16x16x32_f16(af[ks], bf, acc[nt], 0, 0, 0);
        }
    }

    // consume atomic results only now (waitcnt lands after the MFMAs)
    #pragma unroll
    for (int q = 0; q < 2; q++)
        if (doe[q] && (unsigned)slot[q] < CAPS) adj[ci[q] * CAPS + slot[q]] = srcv[q];

    // epilogue: D(row = gr(w*16+quad*4+reg), col = bn + nt*16 + lrow)
    // clamped/duplicate rows write identical values -> benign redundancy
    int ki[4], grs[4];
    #pragma unroll
    for (int reg = 0; reg < 4; reg++) {
        int re = w * 16 + quad * 4 + reg;
        grs[reg] = (z == 0) ? min(bm + re, N - 1) : mask[min(bm + re, M - 1)];
        ki[reg] = key_idx[grs[reg]];
    }
    #pragma unroll
    for (int nt = 0; nt < 4; nt++) {
        int gc = bn + nt * 16 + lrow;
        const float* obc = OB + (size_t)gc * KDIM;
        #pragma unroll
        for (int reg = 0; reg < 4; reg++) {
            int gr = grs[reg];
            float v = acc[nt][reg] + obc[ki[reg]];
            if (gc < 256)      Qbuf[(size_t)gr * 256 + gc] = (_Float16)v;
            else if (gc < 512) Kbuf[(size_t)gr * 256 + (gc - 256)] = (_Float16)v;
            else if (gc < 576) Vbuf[(size_t)gr * KDIM + (gc - 512)] = (_Float16)v;
            else               Sbuf[(size_t)gr * KDIM + (gc - 576)] = v;
        }
    }
}

// 1 wave per output-run (masked node): 4 sub-buckets walked as one concatenated
// list, round-robin across the 4 groups (balanced). 2-deep K/V register
// pipeline via unroll-by-2 with two NAMED register sets (no rotation moves),
// private online-softmax per group, single end-merge,
// fused relu + 64x128 GEMV into d_out. 4 rows/block.
__global__ __launch_bounds__(256) void attend_out(
        const _Float16* __restrict__ Qbuf, const _Float16* __restrict__ Kbuf,
        const _Float16* __restrict__ Vbuf, const float* __restrict__ Sbuf,
        const int* __restrict__ deg4, const int* __restrict__ adj,
        const int* __restrict__ mask, const float* __restrict__ Wo,
        const float* __restrict__ bo, float* __restrict__ out, int M) {
    int w = threadIdx.x >> 6, lane = threadIdx.x & 63;
    int r = blockIdx.x * 4 + w;
    if (r >= M) return;
    int node = mask[r];
    if (r > 0 && mask[r - 1] == node) return;   // duplicate run: start-wave writes it
    int l = lane & 15, g = lane >> 4;

    const uint4* qp = (const uint4*)(Qbuf + (size_t)node * 256 + l * 16);
    uint4 qa = qp[0], qb = qp[1];
    hf2 qh[8] = { bc_h2(qa.x), bc_h2(qa.y), bc_h2(qa.z), bc_h2(qa.w),
                  bc_h2(qb.x), bc_h2(qb.y), bc_h2(qb.z), bc_h2(qb.w) };

    // concatenated-list geometry
    int dn_g = min(deg4[(size_t)node * 4 + g], CAPS);
    int d0 = __shfl(dn_g, 0, 64), d1 = __shfl(dn_g, 16, 64);
    int d2 = __shfl(dn_g, 32, 64), d3 = __shfl(dn_g, 48, 64);
    int O1 = d0, O2 = d0 + d1, O3 = d0 + d1 + d2, T = O3 + d3;
    const size_t base4 = (size_t)node * 4 * CAPS;
    auto fs = [&](int j) -> int {
        int b = (j >= O1) + (j >= O2) + (j >= O3);
        int off = j - (b == 0 ? 0 : b == 1 ? O1 : b == 2 ? O2 : O3);
        return adj[base4 + (size_t)b * CAPS + off];
    };
    // position p (this group's p-th edge) -> adj index, clamped to valid
    auto idxAt = [&](int p) -> int { return fs(min(g + 4 * p, T - 1)); };

    // private per-group state: m, dsum uniform in group; acc = 4 V-cols per lane
    float m = NEG_INF, dsum = 0.f;
    float a0 = 0.f, a1 = 0.f, a2 = 0.f, a3 = 0.f;

    auto compute = [&](uint4 ka, uint4 kb, uint2 vv) {
        float d = 0.f;
        d = dot2acc(bc_h2(ka.x), qh[0], d);
        d = dot2acc(bc_h2(ka.y), qh[1], d);
        d = dot2acc(bc_h2(ka.z), qh[2], d);
        d = dot2acc(bc_h2(ka.w), qh[3], d);
        d = dot2acc(bc_h2(kb.x), qh[4], d);
        d = dot2acc(bc_h2(kb.y), qh[5], d);
        d = dot2acc(bc_h2(kb.z), qh[6], d);
        d = dot2acc(bc_h2(kb.w), qh[7], d);
        d += __shfl_xor(d, 1, 64);
        d += __shfl_xor(d, 2, 64);
        d += __shfl_xor(d, 4, 64);
        d += __shfl_xor(d, 8, 64);
        float sc = d * 0.0625f;              // 1/sqrt(256)
        float m_new = fmaxf(m, sc);
        float scale = __expf(m - m_new);     // first edge: exp(-inf)=0
        float p = __expf(sc - m_new);
        dsum = dsum * scale + p;
        hf2 v01 = bc_h2(vv.x), v23 = bc_h2(vv.y);
        a0 = a0 * scale + p * (float)v01[0];
        a1 = a1 * scale + p * (float)v01[1];
        a2 = a2 * scale + p * (float)v23[0];
        a3 = a3 * scale + p * (float)v23[1];
        m = m_new;
    };

    int P = (g < T) ? ((T - g + 3) >> 2) : 0;   // number of positions for this group
    uint4 kaA = {}, kbA = {}; uint2 vvA = {};
    uint4 kaB = {}, kbB = {}; uint2 vvB = {};
    int sC = 0, sD = 0;
    if (P > 0) {
        int sA = idxAt(0);
        const uint4* kp = (const uint4*)(Kbuf + (size_t)sA * 256 + l * 16);
        kaA = kp[0]; kbA = kp[1];
        vvA = *(const uint2*)(Vbuf + (size_t)sA * KDIM + l * 4);
        int sB = idxAt(1);
        const uint4* kp2 = (const uint4*)(Kbuf + (size_t)sB * 256 + l * 16);
        kaB = kp2[0]; kbB = kp2[1];
        vvB = *(const uint2*)(Vbuf + (size_t)sB * KDIM + l * 4);
        sC = idxAt(2); sD = idxAt(3);
    }
    for (int p = 0; p < P; p += 2) {
        compute(kaA, kbA, vvA);                 // edge position p
        {   // refill A <- position p+2 (clamped-valid speculative load)
            const uint4* kp = (const uint4*)(Kbuf + (size_t)sC * 256 + l * 16);
            kaA = kp[0]; kbA = kp[1];
            vvA = *(const uint2*)(Vbuf + (size_t)sC * KDIM + l * 4);
        }
        int sC2 = idxAt(p + 4);
        if (p + 1 < P) compute(kaB, kbB, vvB);  // edge position p+1
        {   // refill B <- position p+3
            const uint4* kp = (const uint4*)(Kbuf + (size_t)sD * 256 + l * 16);
            kaB = kp[0]; kbB = kp[1];
            vvB = *(const uint2*)(Vbuf + (size_t)sD * KDIM + l * 4);
        }
        int sD2 = idxAt(p + 5);
        sC = sC2; sD = sD2;
    }

    // merge the 4 groups (m, dsum group-uniform)
    float Mx = fmaxf(m, __shfl_xor(m, 16, 64));
    Mx = fmaxf(Mx, __shfl_xor(Mx, 32, 64));
    float wgt = (m == NEG_INF) ? 0.f : __expf(m - Mx);   // empty group / T==0
    float ds = dsum * wgt;
    ds += __shfl_xor(ds, 16, 64);
    ds += __shfl_xor(ds, 32, 64);
    a0 *= wgt; a1 *= wgt; a2 *= wgt; a3 *= wgt;
    a0 += __shfl_xor(a0, 16, 64); a0 += __shfl_xor(a0, 32, 64);
    a1 += __shfl_xor(a1, 16, 64); a1 += __shfl_xor(a1, 32, 64);
    a2 += __shfl_xor(a2, 16, 64); a2 += __shfl_xor(a2, 32, 64);
    a3 += __shfl_xor(a3, 16, 64); a3 += __shfl_xor(a3, 32, 64);
    float inv = 1.f / (ds + 1e-16f);

    // h cols l*4..l*4+3 (identical across groups)
    float4 s4 = *((const float4*)(Sbuf + (size_t)node * KDIM + l * 4));
    float h0 = fmaxf(a0 * inv + s4.x, 0.f);
    float h1 = fmaxf(a1 * inv + s4.y, 0.f);
    float h2 = fmaxf(a2 * inv + s4.z, 0.f);
    float h3 = fmaxf(a3 * inv + s4.w, 0.f);

    // GEMV: out(row) = h @ Wo + bo
    float o0 = bo[lane], o1 = bo[lane + 64];
    #pragma unroll
    for (int c = 0; c < KDIM; c++) {
        float hc = (c & 3) == 0 ? h0 : (c & 3) == 1 ? h1 : (c & 3) == 2 ? h2 : h3;
        float hv = __shfl(hc, c >> 2, 64);
        o0 += hv * Wo[c * DOUT + lane];
        o1 += hv * Wo[c * DOUT + 64 + lane];
    }
    int rr = r;
    do {
        out[(size_t)rr * DOUT + lane] = o0;
        out[(size_t)rr * DOUT + 64 + lane] = o1;
        rr++;
    } while (rr < M && mask[rr] == node);
}

extern "C" void kernel_launch(void* const* d_in, const int* in_sizes, int n_in,
                              void* d_out, int out_size, void* d_ws, size_t ws_size,
                              hipStream_t stream) {
    const float* query    = (const float*)d_in[0];
    const int* key_idx    = (const int*)d_in[1];
    const int* edge_index = (const int*)d_in[2];
    const int* mask_idx   = (const int*)d_in[3];
    const float* Wq = (const float*)d_in[4];
    const float* bq = (const float*)d_in[5];
    const float* Wk = (const float*)d_in[6];
    const float* bk = (const float*)d_in[7];
    const float* Wv = (const float*)d_in[8];
    const float* bv = (const float*)d_in[9];
    const float* Ws = (const float*)d_in[10];
    const float* bs = (const float*)d_in[11];
    const float* Wo = (const float*)d_in[12];
    const float* bo = (const float*)d_in[13];

    int N = in_sizes[0] / QDIM;
    int E = in_sizes[2] / 2;
    int M = in_sizes[3];
    const int* esrc = edge_index;
    const int* edst = edge_index + E;

    char* wsb = (char*)d_ws;
    size_t off = 0;
    auto alloc = [&](size_t nbytes) { char* p = wsb + off; off += (nbytes + 15) & ~15ull; return p; };
    _Float16* Qh   = (_Float16*)alloc((size_t)N * QDIM * 2);
    _Float16* WhT  = (_Float16*)alloc((size_t)NVCOL * QDIM * 2);
    float* OB      = (float*)alloc((size_t)NVCOL * KDIM * 4);
    _Float16* Qbuf = (_Float16*)alloc((size_t)N * 256 * 2);
    _Float16* Kbuf = (_Float16*)alloc((size_t)N * 256 * 2);
    _Float16* Vbuf = (_Float16*)alloc((size_t)N * KDIM * 2);
    float* Sbuf    = (float*)alloc((size_t)N * KDIM * 4);
    int*   deg4    = (int*)alloc((size_t)N * 4 * 4);
    int*   adj     = (int*)alloc((size_t)N * 4 * CAPS * 4);

    int qchunks = N * QDIM / 4;   // float4 chunks of query
    int total1 = qchunks + NVCOL * QDIM + NVCOL * KDIM + 4 * N;
    prep_kernel<<<(total1 + 255) / 256, 256, 0, stream>>>(
        query, Qh, Wq, bq, Wk, bk, Wv, bv, Ws, bs, mask_idx, M, WhT, OB, deg4, qchunks, N);

    int xa = (N + 63) / 64, xm = (M + 63) / 64;
    dim3 ggrid((unsigned)max(xa, xm), 5, 2);   // z=0: K/V all rows; z=1: Q/S masked rows
    gemm_nodes<<<ggrid, 256, 0, stream>>>(Qh, key_idx, WhT, OB, esrc, edst,
                                          mask_idx, M, deg4, adj, E,
                                          Qbuf, Kbuf, Vbuf, Sbuf, N);

    attend_out<<<(M + 3) / 4, 256, 0, stream>>>(Qbuf, Kbuf, Vbuf, Sbuf, deg4, adj,
                                                mask_idx, Wo, bo, (float*)d_out, M);
}